// Round 9
// baseline (271.383 us; speedup 1.0000x reference)
//
#include <hip/hip_runtime.h>
#include <hip/hip_bf16.h>

// GCN fused pipeline for MI355X — dst-bucket grouping + LDS-local E-passes,
// compact-bin AB + readlane finish.
// vocab=1 => h1[i] = relu(embW1*c_i + b1) piecewise-linear in scalar c_i with
// <=65 ReLU patterns (bins). g[i] = a_i*P[bin_i] + b_i*Q[bin_i].
// agg_i[d] = sum_u A_i[u]*P[u][d] + B_i[u]*Q[u][d] over USED bins only (U<<65),
// (A,B) accumulated in LDS (2 LDS atomics/edge). No global atomics on E-scale
// paths (R6: global atomic = 64B HBM line write-through). R8 lesson: LDS pipe
// per-CU is the limiter — so AB is compact-U sized (float4-zeroed) and the
// edge loop does ONE 16B random load (a,b,binc packed in summary4).
// Inputs: 0 x[int32 N], 1 edge_index[int32 2*E] (src then dst), 2 batch[int32 N sorted],
// 3 emb[1*64], 4 W1[64*64], 5 b1[64], 6 W2[64*64], 7 b2[64], 8 fcW[64*32], 9 fcb[32].
// Output: [G=64, 32] fp32.

#define DH 64
#define DOUT 32
#define NBIN 65
#define BW 64          // bucket width (nodes per bucket)
#define MAXNB 2048     // max buckets (N <= 131072)
#define SRCM 0x3FFFFFF // 26-bit src mask (N < 2^26)

// ---- bucket histogram of dst ----
__global__ void k_bhist(const int* __restrict__ dst, int* __restrict__ bhist,
                        int E, int NB) {
    __shared__ int lh[MAXNB];
    for (int t = threadIdx.x; t < NB; t += blockDim.x) lh[t] = 0;
    __syncthreads();
    for (int e = blockIdx.x * blockDim.x + threadIdx.x; e < E; e += gridDim.x * blockDim.x)
        atomicAdd(&lh[dst[e] >> 6], 1);
    __syncthreads();
    for (int t = threadIdx.x; t < NB; t += blockDim.x) {
        int h = lh[t];
        if (h) atomicAdd(&bhist[t], h);
    }
}

// ---- exclusive scan of 2048 bucket counts ----
__global__ void k_bscan(const int* __restrict__ bhist, int* __restrict__ base,
                        int* __restrict__ cursor, int NB, int E) {
    __shared__ int buf[2][MAXNB];
    int t = threadIdx.x;  // 1024
    int v0 = (t < NB) ? bhist[t] : 0;
    int v1 = (t + 1024 < NB) ? bhist[t + 1024] : 0;
    buf[0][t] = v0; buf[0][t + 1024] = v1;
    __syncthreads();
    int cur = 0;
    for (int off = 1; off < MAXNB; off <<= 1) {
        int nxt = cur ^ 1;
        int a = buf[cur][t] + ((t >= off) ? buf[cur][t - off] : 0);
        int b = buf[cur][t + 1024] + ((t + 1024 >= off) ? buf[cur][t + 1024 - off] : 0);
        buf[nxt][t] = a; buf[nxt][t + 1024] = b;
        cur = nxt;
        __syncthreads();
    }
    if (t < NB)        { int ex = buf[cur][t] - v0;        base[t] = ex;        cursor[t] = ex; }
    if (t + 1024 < NB) { int ex = buf[cur][t + 1024] - v1; base[t + 1024] = ex; cursor[t + 1024] = ex; }
    if (t == 0) base[NB] = E;
}

// ---- group edges by dst bucket: packed record = src | (dstlow<<26) ----
__global__ void k_group(const int* __restrict__ src, const int* __restrict__ dst,
                        int* __restrict__ cursor, unsigned* __restrict__ rec,
                        int E, int NB, int chunk) {
    __shared__ int lh[MAXNB];
    __shared__ int lb[MAXNB];
    int c0 = blockIdx.x * chunk;
    int c1 = min(c0 + chunk, E);
    for (int t = threadIdx.x; t < NB; t += blockDim.x) lh[t] = 0;
    __syncthreads();
    for (int e = c0 + threadIdx.x; e < c1; e += blockDim.x)
        atomicAdd(&lh[dst[e] >> 6], 1);
    __syncthreads();
    for (int t = threadIdx.x; t < NB; t += blockDim.x) {
        int h = lh[t];
        lb[t] = h ? atomicAdd(&cursor[t], h) : 0;
    }
    __syncthreads();
    for (int t = threadIdx.x; t < NB; t += blockDim.x) lh[t] = 0;
    __syncthreads();
    for (int e = c0 + threadIdx.x; e < c1; e += blockDim.x) {
        int s = src[e], dd = dst[e];
        int bk = dd >> 6;
        int pos = lb[bk] + atomicAdd(&lh[bk], 1);
        rec[pos] = (unsigned)s | ((unsigned)(dd & 63) << 26);
    }
}

// ---- pass A: per-bucket deg count (LDS) -> dinv ----
__global__ void k_passA(const int* __restrict__ base, const unsigned* __restrict__ rec,
                        float* __restrict__ dinv, int N) {
    __shared__ int cl[BW];
    if (threadIdx.x < BW) cl[threadIdx.x] = 0;
    __syncthreads();
    int b = blockIdx.x;
    int r0 = base[b], r1 = base[b + 1];
    for (int e = r0 + threadIdx.x; e < r1; e += blockDim.x)
        atomicAdd(&cl[rec[e] >> 26], 1);
    __syncthreads();
    if (threadIdx.x < BW) {
        int i = b * BW + threadIdx.x;
        if (i < N) dinv[i] = rsqrtf((float)cl[threadIdx.x] + 1.0f);
    }
}

// ---- fused prep + PQ tables (raw-bin indexed); block 0 exports tarr ----
__global__ void k_tables(const float* __restrict__ emb, const float* __restrict__ W1,
                         const float* __restrict__ b1, const float* __restrict__ W2,
                         float* __restrict__ tarr, float2* __restrict__ PQ) {
    __shared__ float ewl[DH], tl[DH], bl[DH];
    __shared__ int rl[DH], sl[DH];
    int k = threadIdx.x;  // 64
    float s = 0.f;
#pragma unroll
    for (int j = 0; j < DH; ++j) s += emb[j] * W1[j * DH + k];
    float t = (s != 0.f) ? (-b1[k] / s) : INFINITY;
    ewl[k] = s; tl[k] = t; bl[k] = b1[k];
    __syncthreads();
    int r = 0, ss = 0;
#pragma unroll
    for (int j = 0; j < DH; ++j) { r += (tl[j] <= t); ss += (tl[j] < t); }
    rl[k] = r; sl[k] = ss;
    if (blockIdx.x == 0) tarr[k] = t;
    __syncthreads();
    int beta = blockIdx.x;  // 0..64
    float p = 0.f, q = 0.f;
    for (int kk = 0; kk < DH; ++kk) {
        float e = ewl[kk];
        bool act;
        if (e > 0.f) act = (beta >= rl[kk]);
        else if (e < 0.f) act = (beta <= sl[kk]);
        else act = (bl[kk] > 0.f);
        if (act) {
            float w = W2[kk * DH + k];
            p += e * w;
            q += bl[kk] * w;
        }
    }
    PQ[beta * DH + k] = make_float2(p, q);
}

// ---- pass B: per-bucket S (LDS atomics) -> summary4 (a,b,rawbin,0), flags ----
__global__ void k_passB(const int* __restrict__ base, const unsigned* __restrict__ rec,
                        const float* __restrict__ dinv, const float* __restrict__ tarr,
                        float4* __restrict__ summary, int* __restrict__ flags, int N) {
    __shared__ float Sl[BW];
    __shared__ float tl[DH];
    if (threadIdx.x < BW) Sl[threadIdx.x] = 0.f;
    if (threadIdx.x < DH) tl[threadIdx.x] = tarr[threadIdx.x];
    __syncthreads();
    int b = blockIdx.x;
    int r0 = base[b], r1 = base[b + 1];
    for (int e = r0 + threadIdx.x; e < r1; e += blockDim.x) {
        unsigned r = rec[e];
        atomicAdd(&Sl[r >> 26], dinv[r & SRCM]);
    }
    __syncthreads();
    if (threadIdx.x < BW) {
        int i = b * BW + threadIdx.x;
        if (i < N) {
            float di = dinv[i];
            float c = di * (Sl[threadIdx.x] + di);
            int bb = 0;
#pragma unroll
            for (int j = 0; j < DH; ++j) bb += (tl[j] < c);
            summary[i] = make_float4(di * c, di, __uint_as_float((unsigned)bb), 0.f);
            flags[bb] = 1;  // benign race: same value
        }
    }
}

// ---- rewrite summary.z: raw bin -> compact bin (remap from flags ballot) ----
__global__ void k_binc(float4* __restrict__ summary, const int* __restrict__ flags, int N) {
    __shared__ int remap[NBIN];
    if (threadIdx.x < 64) {
        int act = (flags[threadIdx.x] != 0);
        unsigned long long m = __ballot(act);
        remap[threadIdx.x] = __popcll(m & ((1ull << threadIdx.x) - 1ull));
        if (threadIdx.x == 0) remap[64] = __popcll(m);  // bin 64 compacts to the end
    }
    __syncthreads();
    int i = blockIdx.x * blockDim.x + threadIdx.x;
    if (i < N) {
        float4 s = summary[i];
        int rb = __float_as_uint(s.z);
        s.z = __uint_as_float((unsigned)remap[rb]);
        summary[i] = s;
    }
}

// ---- compact PQ: PQc[cidx][d] for used bins (remap recomputed via ballot) ----
__global__ void k_compactPQ(const int* __restrict__ flags, const float2* __restrict__ PQ,
                            float2* __restrict__ PQc) {
    int beta = blockIdx.x, d = threadIdx.x;  // 65 blocks x 64 thr (one wave)
    int act = (flags[d] != 0);
    unsigned long long m = __ballot(act);
    int cidx = (beta < 64) ? __popcll(m & ((1ull << beta) - 1ull)) : __popcll(m);
    bool used = (beta < 64) ? (((m >> beta) & 1ull) != 0) : (flags[64] != 0);
    if (used) PQc[cidx * DH + d] = PQ[beta * DH + d];
}

// ---- pass C: compact-U AB accumulate (2 LDS atomics/edge, 1x16B random read),
// readlane U-dot, self term + relu + sorted-batch strip pooling. block=512. ----
__global__ void k_passC(const int* __restrict__ base, const unsigned* __restrict__ rec,
                        const float4* __restrict__ summary, const float2* __restrict__ PQc,
                        const int* __restrict__ flags, const float* __restrict__ b2,
                        const int* __restrict__ batch, float* __restrict__ psum,
                        float* __restrict__ cnt, int N) {
    __shared__ __align__(16) float AB[BW * NBIN * 2];  // logical stride U, compact
    int tid = threadIdx.x;  // 512
    int lane = tid & 63;
    // every wave computes U identically (cheap, no shared var needed)
    int act = (flags[lane] != 0);
    unsigned long long m = __ballot(act);
    int f64 = (flags[64] != 0);
    int U = __popcll(m) + f64;
    // zero only the used region, float4-wide: 128*U floats = 32*U float4
    int nf4 = 32 * U;
    for (int t = tid; t < nf4; t += blockDim.x) ((float4*)AB)[t] = make_float4(0.f, 0.f, 0.f, 0.f);
    __syncthreads();
    // edge accumulate: one 16B random load per edge, 2 LDS atomics
    int b = blockIdx.x;
    int r0 = base[b], r1 = base[b + 1];
    for (int e = r0 + tid; e < r1; e += blockDim.x) {
        unsigned r = rec[e];
        int s = r & SRCM;
        int dl = r >> 26;
        float4 sm = summary[s];
        int c = __float_as_uint(sm.z);
        float* p = &AB[(dl * U + c) * 2];
        atomicAdd(p, sm.x);
        atomicAdd(p + 1, sm.y);
    }
    __syncthreads();
    // wave w owns nodes [w*8, w*8+8); lane d holds compact-bin column d
    int d = lane;
    int w = tid >> 6;  // 0..7
    int n0b = w << 3;
    float2 abr[8];
#pragma unroll
    for (int j = 0; j < 8; ++j)
        abr[j] = (d < U) ? ((const float2*)AB)[(n0b + j) * U + d] : make_float2(0.f, 0.f);
    float accv[8];
#pragma unroll
    for (int j = 0; j < 8; ++j) accv[j] = 0.f;
    for (int uu = 0; uu < U; ++uu) {
        float2 pq = PQc[uu * DH + d];
        if (uu < 64) {
#pragma unroll
            for (int j = 0; j < 8; ++j) {
                float ax = __int_as_float(__builtin_amdgcn_readlane(__float_as_int(abr[j].x), uu));
                float ay = __int_as_float(__builtin_amdgcn_readlane(__float_as_int(abr[j].y), uu));
                accv[j] += ax * pq.x + ay * pq.y;
            }
        } else {  // only possible when U == 65
#pragma unroll
            for (int j = 0; j < 8; ++j) {
                float2 v = ((const float2*)AB)[(n0b + j) * U + 64];
                accv[j] += v.x * pq.x + v.y * pq.y;
            }
        }
    }
    // finish: self term + relu + sorted-batch strip pooling
    int n0 = b * BW;
    float bias = b2[d];
    float lsum = 0.f, lcnt = 0.f;
    int cb = -1;
    for (int j = 0; j < 8; ++j) {
        int i = n0 + n0b + j;
        if (i >= N) break;
        float4 sm = summary[i];
        int zc = __float_as_uint(sm.z);
        float2 pq = PQc[zc * DH + d];
        float g = sm.x * pq.x + sm.y * pq.y;
        float v = fmaxf(sm.y * (accv[j] + g) + bias, 0.f);
        int bt = batch[i];
        if (bt != cb) {
            if (cb >= 0) {
                atomicAdd(&psum[cb * DH + d], lsum);
                if (d == 0) atomicAdd(&cnt[cb], lcnt);
            }
            cb = bt; lsum = 0.f; lcnt = 0.f;
        }
        lsum += v;
        if (d == 0) lcnt += 1.f;
    }
    if (cb >= 0) {
        atomicAdd(&psum[cb * DH + d], lsum);
        if (d == 0) atomicAdd(&cnt[cb], lcnt);
    }
}

// ---- out[g][o] = (psum[g]/max(cnt,1)) . fcW[:,o] + fcb[o] ----
__global__ void k_out(const float* __restrict__ psum, const float* __restrict__ cnt,
                      const float* __restrict__ fcW, const float* __restrict__ fcb,
                      float* __restrict__ out, int G) {
    int idx = blockIdx.x * blockDim.x + threadIdx.x;
    if (idx >= G * DOUT) return;
    int gi = idx >> 5, o = idx & 31;
    float c = fmaxf(cnt[gi], 1.0f);
    float s = 0.f;
#pragma unroll
    for (int d = 0; d < DH; ++d) s += psum[gi * DH + d] * fcW[d * DOUT + o];
    out[idx] = s / c + fcb[o];
}

static inline size_t pad256(size_t n) { return (n + 255) & ~(size_t)255; }

extern "C" void kernel_launch(void* const* d_in, const int* in_sizes, int n_in,
                              void* d_out, int out_size, void* d_ws, size_t ws_size,
                              hipStream_t stream) {
    const int N = in_sizes[0];
    const int E = in_sizes[1] / 2;
    const int G = out_size / DOUT;
    const int NB = (N + BW - 1) / BW;

    const int* edge = (const int*)d_in[1];
    const int* src = edge;
    const int* dst = edge + E;
    const int* batch = (const int*)d_in[2];
    const float* emb = (const float*)d_in[3];
    const float* W1 = (const float*)d_in[4];
    const float* b1 = (const float*)d_in[5];
    const float* W2 = (const float*)d_in[6];
    const float* b2 = (const float*)d_in[7];
    const float* fcW = (const float*)d_in[8];
    const float* fcb = (const float*)d_in[9];
    float* out = (float*)d_out;

    // workspace. Zero region first: psum, cnt, bhist, flags (small).
    char* ws = (char*)d_ws;
    size_t off = 0;
    float* psum = (float*)(ws + off);  off += pad256((size_t)G * DH) * 4;
    float* cnt  = (float*)(ws + off);  off += pad256(G) * 4;
    int* bhist  = (int*)(ws + off);    off += pad256(MAXNB) * 4;
    int* flags  = (int*)(ws + off);    off += pad256(NBIN) * 4;
    size_t zero_bytes = off;
    int* base    = (int*)(ws + off);    off += pad256(MAXNB + 1) * 4;
    int* cursor  = (int*)(ws + off);    off += pad256(MAXNB) * 4;
    unsigned* rec = (unsigned*)(ws + off); off += pad256(E) * 4;
    float* dinv  = (float*)(ws + off);  off += pad256(N) * 4;
    float* tarr  = (float*)(ws + off);  off += pad256(DH) * 4;
    float2* PQ   = (float2*)(ws + off); off += pad256(NBIN * DH) * 8;
    float2* PQc  = (float2*)(ws + off); off += pad256(NBIN * DH) * 8;
    float4* summary = (float4*)(ws + off); off += pad256(N) * 16;
    // total ~ 9.5 MB

    hipMemsetAsync(d_ws, 0, zero_bytes, stream);

    const int B = 256;
    k_bhist<<<240, B, 0, stream>>>(dst, bhist, E, NB);
    k_bscan<<<1, 1024, 0, stream>>>(bhist, base, cursor, NB, E);
    const int GB = 128;  // spread group's LDS work over 2x CUs vs R8
    int chunk = (E + GB - 1) / GB;
    k_group<<<GB, 1024, 0, stream>>>(src, dst, cursor, rec, E, NB, chunk);
    k_passA<<<NB, B, 0, stream>>>(base, rec, dinv, N);
    k_tables<<<NBIN, DH, 0, stream>>>(emb, W1, b1, W2, tarr, PQ);
    k_passB<<<NB, B, 0, stream>>>(base, rec, dinv, tarr, summary, flags, N);
    k_binc<<<(N + B - 1) / B, B, 0, stream>>>(summary, flags, N);
    k_compactPQ<<<NBIN, DH, 0, stream>>>(flags, PQ, PQc);
    k_passC<<<NB, 512, 0, stream>>>(base, rec, summary, PQc, flags, b2, batch,
                                    psum, cnt, N);
    k_out<<<(G * DOUT + B - 1) / B, B, 0, stream>>>(psum, cnt, fcW, fcb, out, G);
}

// Round 10
// 264.768 us; speedup vs baseline: 1.0250x; 1.0250x over previous
//
#include <hip/hip_runtime.h>
#include <hip/hip_bf16.h>

// GCN fused pipeline for MI355X — dst-bucket grouping + LDS-local E-passes.
// vocab=1 => h1[i] = relu(embW1*c_i + b1) piecewise-linear in scalar c_i with
// <=65 ReLU patterns (bins). g[i] = a_i*P[bin_i] + b_i*Q[bin_i].
// agg_i[d] = sum_u A_i[u]*P[u][d] + B_i[u]*Q[u][d]; per-edge cost: 4B rec read
// + 16B summary read + 2 LDS atomics. Bank-exact LDS layout (R9 lesson):
// separate A/B arrays, bin-major, row stride 65 -> atomic bank (c+dl)%32 and
// gather bank (d+n)%32, both fully spread => ~2-way max (free). Used bins are
// a contiguous raw range [bmin,bmax] (bin(c) monotone) -> no compaction pass.
// No global atomics on E-scale paths (R6: 64B line write-through each).
// Inputs: 0 x[int32 N], 1 edge_index[int32 2*E] (src then dst), 2 batch[int32 N sorted],
// 3 emb[1*64], 4 W1[64*64], 5 b1[64], 6 W2[64*64], 7 b2[64], 8 fcW[64*32], 9 fcb[32].
// Output: [G=64, 32] fp32.

#define DH 64
#define DOUT 32
#define NBIN 65
#define BW 64          // bucket width (nodes per bucket)
#define MAXNB 2048     // max buckets (N <= 131072)
#define SRCM 0x3FFFFFF // 26-bit src mask (N < 2^26)
#define CAP 24         // bins per passC chunk (12.5 KB LDS)

// ---- bucket histogram of dst ----
__global__ void k_bhist(const int* __restrict__ dst, int* __restrict__ bhist,
                        int E, int NB) {
    __shared__ int lh[MAXNB];
    for (int t = threadIdx.x; t < NB; t += blockDim.x) lh[t] = 0;
    __syncthreads();
    for (int e = blockIdx.x * blockDim.x + threadIdx.x; e < E; e += gridDim.x * blockDim.x)
        atomicAdd(&lh[dst[e] >> 6], 1);
    __syncthreads();
    for (int t = threadIdx.x; t < NB; t += blockDim.x) {
        int h = lh[t];
        if (h) atomicAdd(&bhist[t], h);
    }
}

// ---- exclusive scan of 2048 bucket counts ----
__global__ void k_bscan(const int* __restrict__ bhist, int* __restrict__ base,
                        int* __restrict__ cursor, int NB, int E) {
    __shared__ int buf[2][MAXNB];
    int t = threadIdx.x;  // 1024
    int v0 = (t < NB) ? bhist[t] : 0;
    int v1 = (t + 1024 < NB) ? bhist[t + 1024] : 0;
    buf[0][t] = v0; buf[0][t + 1024] = v1;
    __syncthreads();
    int cur = 0;
    for (int off = 1; off < MAXNB; off <<= 1) {
        int nxt = cur ^ 1;
        int a = buf[cur][t] + ((t >= off) ? buf[cur][t - off] : 0);
        int b = buf[cur][t + 1024] + ((t + 1024 >= off) ? buf[cur][t + 1024 - off] : 0);
        buf[nxt][t] = a; buf[nxt][t + 1024] = b;
        cur = nxt;
        __syncthreads();
    }
    if (t < NB)        { int ex = buf[cur][t] - v0;        base[t] = ex;        cursor[t] = ex; }
    if (t + 1024 < NB) { int ex = buf[cur][t + 1024] - v1; base[t + 1024] = ex; cursor[t + 1024] = ex; }
    if (t == 0) base[NB] = E;
}

// ---- group edges by dst bucket: packed record = src | (dstlow<<26) ----
__global__ void k_group(const int* __restrict__ src, const int* __restrict__ dst,
                        int* __restrict__ cursor, unsigned* __restrict__ rec,
                        int E, int NB, int chunk) {
    __shared__ int lh[MAXNB];
    __shared__ int lb[MAXNB];
    int c0 = blockIdx.x * chunk;
    int c1 = min(c0 + chunk, E);
    for (int t = threadIdx.x; t < NB; t += blockDim.x) lh[t] = 0;
    __syncthreads();
    for (int e = c0 + threadIdx.x; e < c1; e += blockDim.x)
        atomicAdd(&lh[dst[e] >> 6], 1);
    __syncthreads();
    for (int t = threadIdx.x; t < NB; t += blockDim.x) {
        int h = lh[t];
        lb[t] = h ? atomicAdd(&cursor[t], h) : 0;
    }
    __syncthreads();
    for (int t = threadIdx.x; t < NB; t += blockDim.x) lh[t] = 0;
    __syncthreads();
    for (int e = c0 + threadIdx.x; e < c1; e += blockDim.x) {
        int s = src[e], dd = dst[e];
        int bk = dd >> 6;
        int pos = lb[bk] + atomicAdd(&lh[bk], 1);
        rec[pos] = (unsigned)s | ((unsigned)(dd & 63) << 26);
    }
}

// ---- pass A: per-bucket deg count (LDS) -> dinv ----
__global__ void k_passA(const int* __restrict__ base, const unsigned* __restrict__ rec,
                        float* __restrict__ dinv, int N) {
    __shared__ int cl[BW];
    if (threadIdx.x < BW) cl[threadIdx.x] = 0;
    __syncthreads();
    int b = blockIdx.x;
    int r0 = base[b], r1 = base[b + 1];
    for (int e = r0 + threadIdx.x; e < r1; e += blockDim.x)
        atomicAdd(&cl[rec[e] >> 26], 1);
    __syncthreads();
    if (threadIdx.x < BW) {
        int i = b * BW + threadIdx.x;
        if (i < N) dinv[i] = rsqrtf((float)cl[threadIdx.x] + 1.0f);
    }
}

// ---- fused prep + PQ tables (raw-bin indexed); block 0 exports tarr ----
__global__ void k_tables(const float* __restrict__ emb, const float* __restrict__ W1,
                         const float* __restrict__ b1, const float* __restrict__ W2,
                         float* __restrict__ tarr, float2* __restrict__ PQ) {
    __shared__ float ewl[DH], tl[DH], bl[DH];
    __shared__ int rl[DH], sl[DH];
    int k = threadIdx.x;  // 64
    float s = 0.f;
#pragma unroll
    for (int j = 0; j < DH; ++j) s += emb[j] * W1[j * DH + k];
    float t = (s != 0.f) ? (-b1[k] / s) : INFINITY;
    ewl[k] = s; tl[k] = t; bl[k] = b1[k];
    __syncthreads();
    int r = 0, ss = 0;
#pragma unroll
    for (int j = 0; j < DH; ++j) { r += (tl[j] <= t); ss += (tl[j] < t); }
    rl[k] = r; sl[k] = ss;
    if (blockIdx.x == 0) tarr[k] = t;
    __syncthreads();
    int beta = blockIdx.x;  // 0..64
    float p = 0.f, q = 0.f;
    for (int kk = 0; kk < DH; ++kk) {
        float e = ewl[kk];
        bool act;
        if (e > 0.f) act = (beta >= rl[kk]);
        else if (e < 0.f) act = (beta <= sl[kk]);
        else act = (bl[kk] > 0.f);
        if (act) {
            float w = W2[kk * DH + k];
            p += e * w;
            q += bl[kk] * w;
        }
    }
    PQ[beta * DH + k] = make_float2(p, q);
}

// ---- pass B: per-bucket S (LDS atomics) -> summary4 (a,b,rawbin,0), flags ----
__global__ void k_passB(const int* __restrict__ base, const unsigned* __restrict__ rec,
                        const float* __restrict__ dinv, const float* __restrict__ tarr,
                        float4* __restrict__ summary, int* __restrict__ flags, int N) {
    __shared__ float Sl[BW];
    __shared__ float tl[DH];
    if (threadIdx.x < BW) Sl[threadIdx.x] = 0.f;
    if (threadIdx.x < DH) tl[threadIdx.x] = tarr[threadIdx.x];
    __syncthreads();
    int b = blockIdx.x;
    int r0 = base[b], r1 = base[b + 1];
    for (int e = r0 + threadIdx.x; e < r1; e += blockDim.x) {
        unsigned r = rec[e];
        atomicAdd(&Sl[r >> 26], dinv[r & SRCM]);
    }
    __syncthreads();
    if (threadIdx.x < BW) {
        int i = b * BW + threadIdx.x;
        if (i < N) {
            float di = dinv[i];
            float c = di * (Sl[threadIdx.x] + di);
            int bb = 0;
#pragma unroll
            for (int j = 0; j < DH; ++j) bb += (tl[j] < c);
            summary[i] = make_float4(di * c, di, __uint_as_float((unsigned)bb), 0.f);
            flags[bb] = 1;  // benign race: same value
        }
    }
}

// ---- pass C: bank-exact A/B accumulate (2 LDS atomics/edge, ~2-way max),
// readlane bin-dot over raw-bin range [bmin,bmax], chunked by CAP,
// self term + relu + sorted-batch strip pooling. block=512, 8 waves x 8 nodes. ----
__global__ void k_passC(const int* __restrict__ base, const unsigned* __restrict__ rec,
                        const float4* __restrict__ summary, const float2* __restrict__ PQ,
                        const int* __restrict__ flags, const float* __restrict__ b2,
                        const int* __restrict__ batch, float* __restrict__ psum,
                        float* __restrict__ cnt, int N) {
    __shared__ float Asm[CAP * 65];
    __shared__ float Bsm[CAP * 65];
    int tid = threadIdx.x;  // 512
    int lane = tid & 63;
    int w = tid >> 6;       // 0..7
    int d = lane;
    // used raw-bin range from flags (per-wave ballot; uniform result)
    int f = (flags[lane] != 0);
    unsigned long long m = __ballot(f);
    int f64 = (flags[64] != 0);
    int bmin = (m != 0ull) ? __builtin_ctzll(m) : 64;
    int bmax = f64 ? 64 : (63 - __builtin_clzll(m));
    int Urange = bmax - bmin + 1;

    int b = blockIdx.x;
    int r0 = base[b], r1 = base[b + 1];
    int n0b = w << 3;
    float accv[8];
#pragma unroll
    for (int j = 0; j < 8; ++j) accv[j] = 0.f;

    for (int cbase = 0; cbase < Urange; cbase += CAP) {
        int clim = min(CAP, Urange - cbase);
        for (int t = tid; t < clim * 65; t += blockDim.x) { Asm[t] = 0.f; Bsm[t] = 0.f; }
        __syncthreads();
        for (int e = r0 + tid; e < r1; e += blockDim.x) {
            unsigned r = rec[e];
            int s = r & SRCM;
            int dl = r >> 26;
            float4 sm = summary[s];
            int c = (int)__float_as_uint(sm.z) - bmin - cbase;
            if ((unsigned)c < (unsigned)clim) {
                atomicAdd(&Asm[c * 65 + dl], sm.x);   // bank (c+dl)%32 — spread
                atomicAdd(&Bsm[c * 65 + dl], sm.y);
            }
        }
        __syncthreads();
        // lane holds chunk-bin = lane; gather its 8 node entries (bank (d+n)%32)
        float ax[8], ay[8];
#pragma unroll
        for (int j = 0; j < 8; ++j) {
            int n = n0b + j;
            ax[j] = (lane < clim) ? Asm[lane * 65 + n] : 0.f;
            ay[j] = (lane < clim) ? Bsm[lane * 65 + n] : 0.f;
        }
        for (int uu = 0; uu < clim; ++uu) {
            float2 pq = PQ[(bmin + cbase + uu) * DH + d];
#pragma unroll
            for (int j = 0; j < 8; ++j) {
                float a = __int_as_float(__builtin_amdgcn_readlane(__float_as_int(ax[j]), uu));
                float bb = __int_as_float(__builtin_amdgcn_readlane(__float_as_int(ay[j]), uu));
                accv[j] += a * pq.x + bb * pq.y;
            }
        }
        __syncthreads();  // safe re-zero for next chunk
    }

    // finish: self term + relu + sorted-batch strip pooling
    int n0 = b * BW;
    float bias = b2[d];
    float lsum = 0.f, lcnt = 0.f;
    int cb = -1;
    for (int j = 0; j < 8; ++j) {
        int i = n0 + n0b + j;
        if (i >= N) break;
        float4 sm = summary[i];
        int rb = (int)__float_as_uint(sm.z);
        float2 pq = PQ[rb * DH + d];
        float g = sm.x * pq.x + sm.y * pq.y;
        float v = fmaxf(sm.y * (accv[j] + g) + bias, 0.f);
        int bt = batch[i];
        if (bt != cb) {
            if (cb >= 0) {
                atomicAdd(&psum[cb * DH + d], lsum);
                if (d == 0) atomicAdd(&cnt[cb], lcnt);
            }
            cb = bt; lsum = 0.f; lcnt = 0.f;
        }
        lsum += v;
        if (d == 0) lcnt += 1.f;
    }
    if (cb >= 0) {
        atomicAdd(&psum[cb * DH + d], lsum);
        if (d == 0) atomicAdd(&cnt[cb], lcnt);
    }
}

// ---- out[g][o] = (psum[g]/max(cnt,1)) . fcW[:,o] + fcb[o] ----
__global__ void k_out(const float* __restrict__ psum, const float* __restrict__ cnt,
                      const float* __restrict__ fcW, const float* __restrict__ fcb,
                      float* __restrict__ out, int G) {
    int idx = blockIdx.x * blockDim.x + threadIdx.x;
    if (idx >= G * DOUT) return;
    int gi = idx >> 5, o = idx & 31;
    float c = fmaxf(cnt[gi], 1.0f);
    float s = 0.f;
#pragma unroll
    for (int d = 0; d < DH; ++d) s += psum[gi * DH + d] * fcW[d * DOUT + o];
    out[idx] = s / c + fcb[o];
}

static inline size_t pad256(size_t n) { return (n + 255) & ~(size_t)255; }

extern "C" void kernel_launch(void* const* d_in, const int* in_sizes, int n_in,
                              void* d_out, int out_size, void* d_ws, size_t ws_size,
                              hipStream_t stream) {
    const int N = in_sizes[0];
    const int E = in_sizes[1] / 2;
    const int G = out_size / DOUT;
    const int NB = (N + BW - 1) / BW;

    const int* edge = (const int*)d_in[1];
    const int* src = edge;
    const int* dst = edge + E;
    const int* batch = (const int*)d_in[2];
    const float* emb = (const float*)d_in[3];
    const float* W1 = (const float*)d_in[4];
    const float* b1 = (const float*)d_in[5];
    const float* W2 = (const float*)d_in[6];
    const float* b2 = (const float*)d_in[7];
    const float* fcW = (const float*)d_in[8];
    const float* fcb = (const float*)d_in[9];
    float* out = (float*)d_out;

    // workspace. Zero region first: psum, cnt, bhist, flags (small).
    char* ws = (char*)d_ws;
    size_t off = 0;
    float* psum = (float*)(ws + off);  off += pad256((size_t)G * DH) * 4;
    float* cnt  = (float*)(ws + off);  off += pad256(G) * 4;
    int* bhist  = (int*)(ws + off);    off += pad256(MAXNB) * 4;
    int* flags  = (int*)(ws + off);    off += pad256(NBIN) * 4;
    size_t zero_bytes = off;
    int* base    = (int*)(ws + off);    off += pad256(MAXNB + 1) * 4;
    int* cursor  = (int*)(ws + off);    off += pad256(MAXNB) * 4;
    unsigned* rec = (unsigned*)(ws + off); off += pad256(E) * 4;
    float* dinv  = (float*)(ws + off);  off += pad256(N) * 4;
    float* tarr  = (float*)(ws + off);  off += pad256(DH) * 4;
    float2* PQ   = (float2*)(ws + off); off += pad256(NBIN * DH) * 8;
    float4* summary = (float4*)(ws + off); off += pad256(N) * 16;
    // total ~ 9 MB

    hipMemsetAsync(d_ws, 0, zero_bytes, stream);

    const int B = 256;
    k_bhist<<<240, B, 0, stream>>>(dst, bhist, E, NB);
    k_bscan<<<1, 1024, 0, stream>>>(bhist, base, cursor, NB, E);
    const int GB = 256;
    int chunk = (E + GB - 1) / GB;
    k_group<<<GB, 512, 0, stream>>>(src, dst, cursor, rec, E, NB, chunk);
    k_passA<<<NB, B, 0, stream>>>(base, rec, dinv, N);
    k_tables<<<NBIN, DH, 0, stream>>>(emb, W1, b1, W2, tarr, PQ);
    k_passB<<<NB, B, 0, stream>>>(base, rec, dinv, tarr, summary, flags, N);
    k_passC<<<NB, 512, 0, stream>>>(base, rec, summary, PQ, flags, b2, batch,
                                    psum, cnt, N);
    k_out<<<(G * DOUT + B - 1) / B, B, 0, stream>>>(psum, cnt, fcW, fcb, out, G);
}